// Round 11
// baseline (211.239 us; speedup 1.0000x reference)
//
#include <hip/hip_runtime.h>
#include <math.h>

// Problem constants
#define N_TOK 16384
#define DDIM  2048
#define NE    64
#define TK    8
#define BT    32              // tokens per block tile
#define NBLK  (N_TOK / BT)    // 512 blocks
#define KSL   256             // K per wave slice (8 slices cover 2048)
#define NCH   8               // chunks per wave slice (32 K each)

// Scaling keeps fp16 split residues normal; logits scaled by 2^17, unscaled
// exactly in the epilogue.
#define XSCALE 64.0f
#define WSCALE 2048.0f
#define LUNSCALE (1.0f / 131072.0f)

// Output layout (flat concat, all fp32)
constexpr size_t OFF_TOP  = 0;
constexpr size_t OFF_SC   = (size_t)N_TOK * TK;
constexpr size_t OFF_IDX  = OFF_SC + (size_t)N_TOK * NE;
constexpr size_t OFF_HIST = OFF_IDX + (size_t)N_TOK * TK;
constexpr size_t OFF_ENT  = OFF_HIST + NE;

#define WLVL (NE * DDIM)                  // 131072 f16 per split level
// Workspace layout
#define HISTC_OFF (1u << 20)              // 512 x 64 int (128 KB), no atomics
#define ENTP_OFF  (HISTC_OFF + (1u << 17))

typedef _Float16 f16x8 __attribute__((ext_vector_type(8)));
typedef float    f32x4  __attribute__((ext_vector_type(4)));
typedef float    f32x16 __attribute__((ext_vector_type(16)));

typedef const __attribute__((address_space(1))) unsigned int gu32;
typedef       __attribute__((address_space(3))) unsigned int lu32;

// 2-level fp16 split: v = h + m + r, |r| <= 2^-22 |v|. v - (float)h is exact.
__device__ __forceinline__ void split2(float v, _Float16& h, _Float16& m) {
    h = (_Float16)v;
    m = (_Float16)(v - (float)h);
}

__device__ __forceinline__ unsigned short f16bits(_Float16 h) {
    union { _Float16 f; unsigned short u; } c; c.f = h; return c.u;
}

// ---------------------------------------------------------------------------
// Prep: w*2048 -> 2-level fp16, 32x32x16 B-fragment-linear layout:
// frag (s16 = k/16, nt = e/32) is 64 lanes x 8 f16; lane = (k/8 % 2)*32 + e%32,
// j = k%8.  offset = ((s16*2+nt)*64 + lane)*8 + j   (+ lev*WLVL)
// ---------------------------------------------------------------------------
__global__ __launch_bounds__(64)
void prep_w(const float* __restrict__ w, unsigned short* __restrict__ wre) {
    int gid = blockIdx.x * 64 + threadIdx.x;   // 16384 threads, 8 elems each
    int e  = gid >> 8;
    int kb = gid & 255;
    int k  = kb * 8;
    const float* wp = w + (size_t)e * DDIM + k;
    float4 f0 = *(const float4*)(wp);
    float4 f1 = *(const float4*)(wp + 4);
    float av[8] = {f0.x, f0.y, f0.z, f0.w, f1.x, f1.y, f1.z, f1.w};

    int s16 = kb >> 1;                 // k/16
    int hi  = kb & 1;                  // (k/8)%2
    int nt  = e >> 5;
    int lane = hi * 32 + (e & 31);
    size_t off = ((size_t)(s16 * 2 + nt) * 64 + lane) * 8;

    unsigned short hb[8], mb[8];
    #pragma unroll
    for (int j = 0; j < 8; ++j) {
        _Float16 h, m;
        split2(av[j] * WSCALE, h, m);
        hb[j] = f16bits(h); mb[j] = f16bits(m);
    }

    #pragma unroll
    for (int lev = 0; lev < 2; ++lev) {
        const unsigned short* src = lev ? mb : hb;
        uint4 v;
        v.x = (unsigned)src[0] | ((unsigned)src[1] << 16);
        v.y = (unsigned)src[2] | ((unsigned)src[3] << 16);
        v.z = (unsigned)src[4] | ((unsigned)src[5] << 16);
        v.w = (unsigned)src[6] | ((unsigned)src[7] << 16);
        *(uint4*)(wre + (size_t)lev * WLVL + off) = v;
    }
}

// ---------------------------------------------------------------------------
// Fused GEMM + epilogue.  512 blocks x 512 threads (8 waves), 2 blocks/CU.
// Identical to the best-known (209/211 us) structure EXCEPT the main loop
// is barrier-free: staging is wave-private (wave wid DMAs and reads only
// its own slab), so the per-chunk __syncthreads synchronized nothing --
// it only forced a full vmcnt(0)+lgkmcnt(0) drain (killing the B ring and
// DMA pipeline) and convoyed all blocks' HBM bursts.  Replaced with a
// per-wave counted wait:
//   end of iter c:  s_waitcnt vmcnt(8)   // retires stage(c+1)'s 4 DMA;
//                                        // keeps 8 B-loads in flight
// Count is exact: ops issued after stage(c+1) = 2 loadB quads = 8; the
// unrolled loop contains no other VMEM ops; vmcnt is in-order.
// sched_barrier(0) fences pin region order (rule #18).
// ---------------------------------------------------------------------------
__global__ __launch_bounds__(512, 4)
void router_fused(const float* __restrict__ x,
                  const unsigned short* __restrict__ wre,
                  const float* __restrict__ bias,
                  float* __restrict__ out,
                  int* __restrict__ histc,
                  float* __restrict__ entp)
{
    union SMem {
        float As[2][8192];            // [buf][wid*1024 + (row*8+g)*4f], 64 KB
        struct {
            float pl[16][16][64];     // [w*2+nt][reg][lane] partials, 64 KB
            float sct[NE][BT + 1];    // scores [expert][token]
            float bsh[NE];            // (beyond As's 64 KB: safe early init)
            int   hist[NE];
            float entw[2];
        } ep;                          // ~74.5 KB -> 2 blocks/CU
    };
    __shared__ SMem sm;

    const int tid  = threadIdx.x;
    const int lane = tid & 63;
    const int wid  = tid >> 6;      // K-slice 0..7
    const int t0b  = blockIdx.x * BT;
    const int row  = lane & 31;     // token row in A fragment
    const int hi   = lane >> 5;     // k-subgroup

    if (tid < NE) { sm.ep.bsh[tid] = bias[tid]; sm.ep.hist[tid] = 0; }

    // Staging source: lane l covers row (l>>3) (+8 per op), granule
    // (l&7)^((l>>3)&7)  (XOR pre-swizzle; 128B segment per 8 lanes).
    const float* xrow = x + (size_t)(t0b + (lane >> 3)) * DDIM + wid * KSL
                          + (((lane & 7) ^ ((lane >> 3) & 7)) << 2);
    const unsigned short* wl = wre + (size_t)lane * 8;
    const int s16b = wid * (KSL / 16);  // global 16-K step base

    f32x16 acc[2];
    #pragma unroll
    for (int i = 0; i < 16; ++i) { acc[0][i] = 0.f; acc[1][i] = 0.f; }

    // Stage chunk c into buffer buf: 4 ops x 1 KB, each op = 8 full rows.
    // Wave-private: dest slab = As[buf][wid*1024..], read by this wave only.
    auto stage = [&](int c, int buf) {
        #pragma unroll
        for (int i = 0; i < 4; ++i) {
            const float* g = xrow + (size_t)i * 8 * DDIM + c * 32;
            __builtin_amdgcn_global_load_lds((gu32*)g,
                (lu32*)&sm.As[buf][wid * 1024 + i * 256], 16, 0, 0);
        }
    };
    // B frags for 16-K step: [0]=bh nt0, [1]=bh nt1, [2]=bm nt0, [3]=bm nt1
    auto loadB = [&](int s, f16x8 (&B)[4]) {
        #pragma unroll
        for (int f = 0; f < 4; ++f)
            B[f] = *(const f16x8*)(wl + (size_t)(f >> 1) * WLVL
                                      + ((size_t)((s16b + s) * 2 + (f & 1)) << 9));
    };
    auto computeStep = [&](const float4* As4, int s, const f16x8 (&B)[4]) {
        const int g0 = s * 4 + hi * 2;
        float4 G0 = As4[(row << 3) + ( g0      ^ (row & 7))];  // swizzled read
        float4 G1 = As4[(row << 3) + ((g0 + 1) ^ (row & 7))];
        float av[8] = {G0.x, G0.y, G0.z, G0.w, G1.x, G1.y, G1.z, G1.w};
        f16x8 ah, am;
        #pragma unroll
        for (int j = 0; j < 8; ++j) {
            _Float16 h, m;
            split2(av[j] * XSCALE, h, m);
            ah[j] = h; am[j] = m;
        }
        #pragma unroll
        for (int nt = 0; nt < 2; ++nt) {
            acc[nt] = __builtin_amdgcn_mfma_f32_32x32x16_f16(ah, B[nt],     acc[nt], 0, 0, 0);
            acc[nt] = __builtin_amdgcn_mfma_f32_32x32x16_f16(am, B[nt],     acc[nt], 0, 0, 0);
            acc[nt] = __builtin_amdgcn_mfma_f32_32x32x16_f16(ah, B[2 + nt], acc[nt], 0, 0, 0);
            acc[nt] = __builtin_amdgcn_mfma_f32_32x32x16_f16(am, B[2 + nt], acc[nt], 0, 0, 0);
        }
    };

    f16x8 Bb[2][4];                  // step t lives in Bb[t&1]
    stage(0, 0);                     // 4 DMA
    __builtin_amdgcn_sched_barrier(0);
    loadB(0, Bb[0]);                 // 4 B-loads
    __builtin_amdgcn_sched_barrier(0);
    // retire stage(0) (ops since its last DMA: loadB(0)'s 4):
    asm volatile("s_waitcnt vmcnt(4)" ::: "memory");
    __builtin_amdgcn_sched_barrier(0);

    #pragma unroll
    for (int c = 0; c < NCH; ++c) {
        const int buf = c & 1;
        if (c + 1 < NCH) stage(c + 1, buf ^ 1);   // issue next chunk DMA
        __builtin_amdgcn_sched_barrier(0);
        const float4* As4 = (const float4*)&sm.As[buf][wid * 1024];
        // step 0 of chunk: prefetch B for step 1, pin, compute
        loadB(c * 2 + 1, Bb[1]);
        __builtin_amdgcn_sched_barrier(0);
        computeStep(As4, 0, Bb[0]);
        // step 1: prefetch B for next chunk's step 0, pin, compute
        if (c + 1 < NCH) loadB(c * 2 + 2, Bb[0]);
        __builtin_amdgcn_sched_barrier(0);
        computeStep(As4, 1, Bb[1]);
        if (c + 1 < NCH) {
            // per-wave wait: retire stage(c+1)'s 4 DMA (8 B-loads younger
            // stay in flight); no block-wide coupling, no full drain.
            asm volatile("s_waitcnt vmcnt(8)" ::: "memory");
            __builtin_amdgcn_sched_barrier(0);
        }
    }

    // ---- epilogue (all waves must be done with As before pl overlays it) --
    __syncthreads();
    // C/D: col(expert%32)=lane&31, row(token)=(reg&3)+8*(reg>>2)+4*(lane>>5).
    #pragma unroll
    for (int nt = 0; nt < 2; ++nt)
        #pragma unroll
        for (int r = 0; r < 16; ++r)
            sm.ep.pl[wid * 2 + nt][r][lane] = acc[nt][r];
    __syncthreads();

    // Combine 8 K-slices (fixed order), sigmoid, score store (coalesced).
    {
        const int tok = tid >> 4;               // 0..31
        const int e0  = (tid & 15) * 4;         // 0..60
        const int nt  = e0 >> 5;
        const int r   = (tok & 3) | ((tok >> 3) << 2);
        const int ln  = ((tok >> 2) & 1) * 32 + (e0 & 31);
        f32x4 s4 = {0.f, 0.f, 0.f, 0.f};
        #pragma unroll
        for (int w = 0; w < 8; ++w)
            s4 += *(const f32x4*)&sm.ep.pl[w * 2 + nt][r][ln];
        float4 sv;
        sv.x = 1.0f / (1.0f + expf(-s4[0] * LUNSCALE));
        sv.y = 1.0f / (1.0f + expf(-s4[1] * LUNSCALE));
        sv.z = 1.0f / (1.0f + expf(-s4[2] * LUNSCALE));
        sv.w = 1.0f / (1.0f + expf(-s4[3] * LUNSCALE));
        sm.ep.sct[e0 + 0][tok] = sv.x;
        sm.ep.sct[e0 + 1][tok] = sv.y;
        sm.ep.sct[e0 + 2][tok] = sv.z;
        sm.ep.sct[e0 + 3][tok] = sv.w;
        *(float4*)&out[OFF_SC + (size_t)(t0b + tok) * NE + e0] = sv;
    }
    __syncthreads();

    // Top-8: waves 0-1; lane = expert-group x 16 tokens.
    float entv = 0.f;
    if (wid < 2) {
        const int tl = wid * 16 + (lane & 15);
        const int eg = lane >> 4;               // expert group of 16
        float v[16];
        #pragma unroll
        for (int i = 0; i < 16; ++i)
            v[i] = sm.ep.sct[eg * 16 + i][tl] + sm.ep.bsh[eg * 16 + i];

        float ch[TK]; int ci[TK]; float ssum = 0.f;
        #pragma unroll
        for (int p = 0; p < TK; ++p) {
            float bv = v[0]; int bi = 0;
            #pragma unroll
            for (int i = 1; i < 16; ++i) {      // strict '>': lowest idx on tie
                const bool sgt = v[i] > bv;
                bv = sgt ? v[i] : bv;
                bi = sgt ? i : bi;
            }
            int be = eg * 16 + bi;
            {   // combine groups: lane^16 (same token, other group)
                float ov = __shfl_xor(bv, 16);
                int   oe = __shfl_xor(be, 16);
                const bool tk = (ov > bv) || (ov == bv && oe < be);
                bv = tk ? ov : bv; be = tk ? oe : be;
            }
            {   // lane^32
                float ov = __shfl_xor(bv, 32);
                int   oe = __shfl_xor(be, 32);
                const bool tk = (ov > bv) || (ov == bv && oe < be);
                bv = tk ? ov : bv; be = tk ? oe : be;
            }
            #pragma unroll
            for (int i = 0; i < 16; ++i)        // static-index mask (rule #20)
                v[i] = (be == eg * 16 + i) ? -1e30f : v[i];
            const float sc = sm.ep.sct[be][tl]; // unbiased score
            ch[p] = sc; ci[p] = be; ssum += sc;
        }
        if (eg == 0) {
            const float inv = 1.0f / (ssum + 1e-20f);
            #pragma unroll
            for (int p = 0; p < TK; ++p) {
                atomicAdd(&sm.ep.hist[ci[p]], 1);   // LDS atomic only
                const float pn = ch[p] * inv;   // ROUTE_SCALE == 1.0
                out[OFF_TOP + (size_t)(t0b + tl) * TK + p] = pn;
                out[OFF_IDX + (size_t)(t0b + tl) * TK + p] = (float)ci[p];
                entv += pn * logf(pn);
            }
        }
        entv += __shfl_down(entv, 8);
        entv += __shfl_down(entv, 4);
        entv += __shfl_down(entv, 2);
        entv += __shfl_down(entv, 1);
        if (lane == 0) sm.ep.entw[wid] = entv;
    }
    __syncthreads();

    // Per-block partials: plain coalesced stores, NO global atomics.
    if (tid == 0) entp[blockIdx.x] = sm.ep.entw[0] + sm.ep.entw[1];
    if (tid < NE) histc[blockIdx.x * NE + tid] = sm.ep.hist[tid];
}

// ---------------------------------------------------------------------------
// Finalize: reduce per-block histogram rows and entropy partials.
// ---------------------------------------------------------------------------
__global__ __launch_bounds__(256)
void finalize(const int* __restrict__ histc,
              const float* __restrict__ entp,
              float* __restrict__ out)
{
    __shared__ int   hred[4][NE];
    __shared__ float ered[256];
    const int tid = threadIdx.x;
    {
        const int e = tid & 63, p = tid >> 6;   // 4 partitions x 128 blocks
        int s = 0;
        for (int b = p * 128; b < p * 128 + 128; ++b)
            s += histc[b * NE + e];
        hred[p][e] = s;
    }
    float ev = 0.f;
    for (int i = tid; i < NBLK; i += 256) ev += entp[i];
    ered[tid] = ev;
    __syncthreads();
    if (tid < NE)
        out[OFF_HIST + tid] =
            (float)(hred[0][tid] + hred[1][tid] + hred[2][tid] + hred[3][tid]);
    #pragma unroll
    for (int o = 128; o > 0; o >>= 1) {
        if (tid < o) ered[tid] += ered[tid + o];
        __syncthreads();
    }
    if (tid == 0) out[OFF_ENT] = -ered[0] * (1.0f / (float)N_TOK);
}

extern "C" void kernel_launch(void* const* d_in, const int* in_sizes, int n_in,
                              void* d_out, int out_size, void* d_ws, size_t ws_size,
                              hipStream_t stream) {
    const float* x    = (const float*)d_in[0];   // [16384, 2048]
    const float* w    = (const float*)d_in[1];   // [64, 2048]
    const float* bias = (const float*)d_in[2];   // [64]
    float* out = (float*)d_out;
    unsigned short* wre = (unsigned short*)d_ws;            // 512 KB (2 levels)
    int*   histc = (int*)  ((char*)d_ws + HISTC_OFF);
    float* entp  = (float*)((char*)d_ws + ENTP_OFF);

    prep_w      <<<dim3(256),  dim3(64),  0, stream>>>(w, wre);
    router_fused<<<dim3(NBLK), dim3(512), 0, stream>>>(x, wre, bias, out,
                                                       histc, entp);
    finalize    <<<dim3(1),    dim3(256), 0, stream>>>(histc, entp, out);
}